// Round 25
// baseline (263.872 us; speedup 1.0000x reference)
//
#include <hip/hip_runtime.h>
#include <hip/hip_bf16.h>

#define N_NODES 25000
#define N_EDGES 100000
#define E_PAD   100032   // 1563 * 64
#define NSCB    98       // ceil(N_NODES/256) scan blocks
#define NHB     391      // ceil(N_EDGES/256) histogram blocks

typedef __attribute__((ext_vector_type(8))) short bf16x8;
typedef __attribute__((ext_vector_type(4))) float f32x4;

__device__ __forceinline__ unsigned short f2bf(float v) {
  __hip_bfloat16 hb = __float2bfloat16(v);
  return *reinterpret_cast<unsigned short*>(&hb);
}
__device__ __forceinline__ float bf2f(unsigned short u) {
  return __uint_as_float(((unsigned)u) << 16);
}

// Fused prep: blocks [0,128): W2 -> bf16 packed B-fragments (coalesced
// (i,w,s,lane) order). Blocks [128, 128+6250): node prep out/xb/ab1/ab2.
// Blocks [6378, 6378+391): deg histogram from dst (deg zeroed by memset).
__global__ __launch_bounds__(256) void k_pre(const float* __restrict__ x,
    const float* __restrict__ root, const float* __restrict__ b2,
    const float* __restrict__ att, const float* __restrict__ bias,
    const float* __restrict__ W2, const int* __restrict__ ei,
    unsigned char* __restrict__ w2pk,
    float* __restrict__ out, float* __restrict__ xb,
    float* __restrict__ ab1, float* __restrict__ ab2,
    unsigned* __restrict__ deg) {
  __shared__ float lxb[4][64];
  int b = blockIdx.x;
  if (b < 128) {
    int g = b * 256 + threadIdx.x;                 // 32768 threads
    int lane = g & 63, s = (g >> 6) & 3, w = (g >> 8) & 3, i = g >> 10;
    int col = i * 64 + w * 16 + (lane & 15);
    int k0 = s * 32 + (lane >> 4) * 8;
    bf16x8 v;
    #pragma unroll
    for (int j = 0; j < 8; ++j)
      v[j] = (short)f2bf(W2[(size_t)(k0 + j) * 2048 + col]);
    *(bf16x8*)(w2pk + (size_t)g * 16) = v;         // linear: coalesced store
    return;
  }
  if (b >= 128 + 6250) {
    int e = (b - 128 - 6250) * 256 + threadIdx.x;
    if (e < N_EDGES) atomicAdd(deg + ei[N_EDGES + e], 1u);
    return;
  }
  int g = (b - 128) * 256 + threadIdx.x;           // N*64 exact
  int n = g >> 6, o = g & 63;
  const float* xr = x + (size_t)n * 32;
  float ra = bias[o], xa = 0.f;
  #pragma unroll
  for (int i = 0; i < 32; ++i) {
    float xv = xr[i];
    ra += xv * root[i * 64 + o];
    xa += xv * b2[i * 64 + o];
  }
  out[g] = ra;
  xb[g] = xa;
  int ln = threadIdx.x >> 6;
  lxb[ln][o] = xa;
  __syncthreads();
  if (o < 8) {
    int hd = o;
    float s1 = 0.f, s2 = 0.f;
    #pragma unroll
    for (int c = 0; c < 8; ++c) {
      float v = lxb[ln][hd * 8 + c];
      s1 += v * att[hd * 16 + c];
      s2 += v * att[hd * 16 + 8 + c];
    }
    size_t idx = (size_t)n * 8 + hd;
    ab1[idx] = s1; ab2[idx] = s2;
  }
}

// R22/R24 k_main with waves_per_eu(2) -> (4): budget 128 >= 84 natural
// pressure, so codegen should be unchanged — tests whether the residency
// cap (measured 2 waves/EU, exactly the old attr min) follows the attr.
__global__ __launch_bounds__(256)
__attribute__((amdgpu_waves_per_eu(4)))
void k_main(
    const float* __restrict__ x, const int* __restrict__ ei,
    const float* __restrict__ ef, const float* __restrict__ W1,
    const float* __restrict__ b1,
    const float* __restrict__ att, const float* __restrict__ ab1,
    const float* __restrict__ ab2,
    const unsigned char* __restrict__ w2pk,
    unsigned short* __restrict__ xj_out, float* __restrict__ alpha_out) {
  __shared__ unsigned char lds_h[16384];   // 16 frags x 64 lanes x 16B, linear
  __shared__ float lds_xs[32 * 64];        // [ch][edge] x[src] transposed, f32
  __shared__ float lds_xd[32 * 64];        // [ch][edge] x[dst] transposed, f32
  const int tid = threadIdx.x;
  const int lane = tid & 63;
  const int w = tid >> 6;                  // wave id: owns output cols w*16..+15
  const int e0 = blockIdx.x * 64;
  const int* srcp = ei;
  const int* dstp = ei + N_EDGES;

  // ---- inline h via MFMA (R13 verbatim, proven) ----
  {
    const int l15 = lane & 15;
    const int k0 = (lane >> 4) * 8;
    bf16x8 ha[4], hb[2];
    #pragma unroll
    for (int mt = 0; mt < 4; ++mt) {
      int e = e0 + mt * 16 + l15;
      if (e >= N_EDGES) e = N_EDGES - 1;   // clamped rows masked later
      bf16x8 v;
      if (k0 < 16) {
        const float* ap = ef + (size_t)e * 16 + k0;
        f32x4 a0 = *(const f32x4*)(ap);
        f32x4 a1 = *(const f32x4*)(ap + 4);
        #pragma unroll
        for (int t = 0; t < 4; ++t) {
          v[t]     = (short)f2bf(a0[t]);
          v[t + 4] = (short)f2bf(a1[t]);
        }
      } else {
        #pragma unroll
        for (int t = 0; t < 8; ++t) v[t] = 0;
      }
      ha[mt] = v;
    }
    #pragma unroll
    for (int nt = 0; nt < 2; ++nt) {
      int col = w * 32 + nt * 16 + l15;
      bf16x8 v;
      if (k0 < 16) {
        #pragma unroll
        for (int j = 0; j < 8; ++j)
          v[j] = (short)f2bf(W1[(k0 + j) * 128 + col]);
      } else {
        #pragma unroll
        for (int j = 0; j < 8; ++j) v[j] = 0;
      }
      hb[nt] = v;
    }
    const int lpb = (lane >> 4) * 4;               // output row base within 16
    const int byt = (lane & 7) * 2;                // byte within 16B frag slot
    #pragma unroll
    for (int nt = 0; nt < 2; ++nt) {
      float bv = b1[w * 32 + nt * 16 + l15];
      const int hi = (nt * 2 + (l15 >> 3)) << 4;   // reader-lane hi nibble
      #pragma unroll
      for (int mt = 0; mt < 4; ++mt) {
        f32x4 acc = {bv, bv, bv, bv};
        acc = __builtin_amdgcn_mfma_f32_16x16x32_bf16(ha[mt], hb[nt], acc, 0, 0, 0);
        unsigned base = (unsigned)(mt * 4 + w) * 1024u + (unsigned)hi * 16u + (unsigned)byt;
        #pragma unroll
        for (int r = 0; r < 4; ++r) {
          float hv = acc[r] > 0.f ? acc[r] : 0.f;
          *(unsigned short*)(lds_h + base + (lpb + r) * 16) = f2bf(hv);
        }
      }
    }
  }

  // ---- gather x rows for src/dst (transposed into LDS, f32) ----
  {
    int m = tid & 63;
    int half = (tid >> 6) & 1;
    int which = tid >> 7;
    int eIdx = e0 + m; if (eIdx >= N_EDGES) eIdx = N_EDGES - 1;
    int node = which ? dstp[eIdx] : srcp[eIdx];
    const f32x4* xr = (const f32x4*)(x + (size_t)node * 32 + half * 16);
    float* lx = which ? lds_xd : lds_xs;
    #pragma unroll
    for (int q = 0; q < 4; ++q) {
      f32x4 vv = xr[q];
      int i0 = half * 16 + q * 4;
      #pragma unroll
      for (int j = 0; j < 4; ++j) lx[(i0 + j) * 64 + m] = vv[j];
    }
  }
  __syncthreads();

  // ---- K-loop: pair-amortized, coalesced B-loads ----
  const unsigned char* bgp = w2pk + (size_t)w * 4096 + (size_t)lane * 16;
  f32x4 xj_acc[4] = {};
  f32x4 xi_acc[4] = {};
  const int rg4 = ((lane >> 4) & 3) * 4;
  const int lb16 = lane * 16;

  #pragma unroll 1
  for (int p = 0; p < 16; ++p) {
    const int i = 2 * p;
    bf16x8 bA[4], bB[4];
    #pragma unroll
    for (int s = 0; s < 4; ++s) {
      bA[s] = *(const bf16x8*)(bgp + (size_t)i * 16384 + s * 1024);
      bB[s] = *(const bf16x8*)(bgp + (size_t)(i + 1) * 16384 + s * 1024);
    }
    #pragma unroll
    for (int mt = 0; mt < 4; ++mt) {
      f32x4 gA = {0.f, 0.f, 0.f, 0.f};
      f32x4 gB = {0.f, 0.f, 0.f, 0.f};
      #pragma unroll
      for (int s = 0; s < 4; ++s) {
        bf16x8 a = *(const bf16x8*)(lds_h + (mt * 4 + s) * 1024 + lb16);
        gA = __builtin_amdgcn_mfma_f32_16x16x32_bf16(a, bA[s], gA, 0, 0, 0);
        gB = __builtin_amdgcn_mfma_f32_16x16x32_bf16(a, bB[s], gB, 0, 0, 0);
      }
      f32x4 xsv0 = *(const f32x4*)(lds_xs + i * 64 + mt * 16 + rg4);
      f32x4 xdv0 = *(const f32x4*)(lds_xd + i * 64 + mt * 16 + rg4);
      f32x4 xsv1 = *(const f32x4*)(lds_xs + (i + 1) * 64 + mt * 16 + rg4);
      f32x4 xdv1 = *(const f32x4*)(lds_xd + (i + 1) * 64 + mt * 16 + rg4);
      #pragma unroll
      for (int r = 0; r < 4; ++r) {
        xj_acc[mt][r] += xsv0[r] * gA[r] + xsv1[r] * gB[r];
        xi_acc[mt][r] += xdv0[r] * gA[r] + xdv1[r] * gB[r];
      }
    }
  }

  // ---- epilogue: xj bf16 store + logits ----
  const int h2 = (lane >> 3) & 1;
  const int cc = lane & 7;
  const int head = 2 * w + h2;
  const float a1v = att[head * 16 + cc];
  const float a2v = att[head * 16 + 8 + cc];
  #pragma unroll
  for (int mt = 0; mt < 4; ++mt) {
    #pragma unroll
    for (int r = 0; r < 4; ++r) {
      int row = mt * 16 + rg4 + r;
      int eIdx = e0 + row;
      xj_out[(size_t)eIdx * 64 + w * 16 + (lane & 15)] = f2bf(xj_acc[mt][r]);
      float v = xi_acc[mt][r] * a1v + xj_acc[mt][r] * a2v;
      v += __shfl_xor(v, 1);
      v += __shfl_xor(v, 2);
      v += __shfl_xor(v, 4);
      if (cc == 0 && eIdx < N_EDGES) {
        int d = dstp[eIdx];
        float lg = v + ab1[(size_t)d * 8 + head] + ab2[(size_t)srcp[eIdx] * 8 + head];
        lg = lg > 0.f ? lg : 0.2f * lg;
        alpha_out[(size_t)eIdx * 8 + head] = lg;
      }
    }
  }
}

// Block-local exclusive scan of deg + one atomicAdd(gbase) per block for the
// absolute segment base (arrival order; contiguity is all that matters).
__global__ __launch_bounds__(256) void k_scan(const unsigned* __restrict__ deg,
    unsigned* __restrict__ off, unsigned* __restrict__ gbase) {
  __shared__ unsigned sd[256];
  __shared__ unsigned blockbase;
  int tid = threadIdx.x;
  int n = blockIdx.x * 256 + tid;
  unsigned v = (n < N_NODES) ? deg[n] : 0u;
  sd[tid] = v;
  __syncthreads();
  #pragma unroll
  for (int ofs = 1; ofs < 256; ofs <<= 1) {
    unsigned t = (tid >= ofs) ? sd[tid - ofs] : 0u;
    __syncthreads();
    sd[tid] += t;
    __syncthreads();
  }
  if (tid == 255) blockbase = atomicAdd(gbase, sd[255]);
  __syncthreads();
  if (n < N_NODES) off[n] = blockbase + sd[tid] - v;   // absolute segment start
}

// Fill CSR edge lists: pos = off[d]++ (off[n] ends at segment end; k_agg
// recovers base = off[n] - deg[n]).
__global__ __launch_bounds__(256) void k_fill(const int* __restrict__ ei,
    unsigned* __restrict__ off, unsigned* __restrict__ elist) {
  int e = blockIdx.x * 256 + threadIdx.x;
  if (e >= N_EDGES) return;
  int d = ei[N_EDGES + e];
  unsigned pos = atomicAdd(off + d, 1u);
  elist[pos] = (unsigned)e;
}

// Gather-aggregate: per (node, o): softmax over incoming edges (2 uniform
// loops, wave = exactly one node), + deg*bias, + ELU. No atomics.
__global__ __launch_bounds__(256) void k_agg(const unsigned* __restrict__ off,
    const unsigned* __restrict__ deg,
    const unsigned* __restrict__ elist, const float* __restrict__ alpha,
    const unsigned short* __restrict__ xj, const float* __restrict__ bias,
    float* __restrict__ out) {
  int g = blockIdx.x * 256 + threadIdx.x;          // N*64 exact
  int n = g >> 6, o = g & 63, hd = o >> 3;
  unsigned dg = deg[n];
  unsigned base = off[n] - dg;                     // off ended at segment end
  float m = -1e30f;
  for (unsigned j = 0; j < dg; ++j) {
    unsigned e = elist[base + j];
    m = fmaxf(m, alpha[(size_t)e * 8 + hd]);
  }
  float s = 0.f, acc = 0.f;
  for (unsigned j = 0; j < dg; ++j) {
    unsigned e = elist[base + j];
    float p = expf(alpha[(size_t)e * 8 + hd] - m);
    s += p;
    acc += p * bf2f(xj[(size_t)e * 64 + o]);
  }
  float val = out[g] + acc / (s + 1e-16f) + (float)dg * bias[o];
  out[g] = val > 0.f ? val : expm1f(val);
}

extern "C" void kernel_launch(void* const* d_in, const int* in_sizes, int n_in,
                              void* d_out, int out_size, void* d_ws, size_t ws_size,
                              hipStream_t stream) {
  const float* x    = (const float*)d_in[0];
  const int*   eidx = (const int*)d_in[1];
  const float* ef   = (const float*)d_in[2];
  const float* W1   = (const float*)d_in[3];
  const float* b1   = (const float*)d_in[4];
  const float* W2   = (const float*)d_in[5];
  const float* b2   = (const float*)d_in[6];
  const float* att  = (const float*)d_in[7];
  const float* bias = (const float*)d_in[8];
  const float* root = (const float*)d_in[9];
  float* out = (float*)d_out;
  char* ws = (char*)d_ws;

  // workspace layout (256B aligned), total ~25.2 MB
  unsigned char* w2pk = (unsigned char*)(ws + 0);           // 512 KB packed B-frags
  float* xb    = (float*)(ws + 524288);                     // N*64 f32
  float* ab1   = (float*)(ws + 6924288);                    // N*8 f32
  float* ab2   = (float*)(ws + 7724288);                    // N*8 f32
  unsigned short* xj_ws = (unsigned short*)(ws + 8524288);  // E_PAD*64 bf16
  float* al_ws = (float*)(ws + 21328384);                   // E_PAD*8 f32
  unsigned* deg   = (unsigned*)(ws + 24529408);             // N u32 (pad 100352)
  unsigned* gbase = (unsigned*)(ws + 24629760);             // 1 u32 (pad 256)
  unsigned* off   = (unsigned*)(ws + 24630016);             // N u32 (pad 100352)
  unsigned* elist = (unsigned*)(ws + 24730368);             // E u32

  hipMemsetAsync(deg, 0, 100352 + 256, stream);             // deg + gbase
  k_pre  <<<128 + 6250 + NHB, 256, 0, stream>>>(x, root, b2, att, bias,
                                                W2, eidx, w2pk, out, xb, ab1, ab2, deg);
  k_main <<<E_PAD / 64, 256, 0, stream>>>(x, eidx, ef, W1, b1, att, ab1, ab2,
                                          w2pk, xj_ws, al_ws);
  k_scan <<<NSCB, 256, 0, stream>>>(deg, off, gbase);
  k_fill <<<NHB, 256, 0, stream>>>(eidx, off, elist);
  k_agg  <<<N_NODES * 64 / 256, 256, 0, stream>>>(off, deg, elist, al_ws,
                                                  xj_ws, bias, out);
}

// Round 26
// 150.767 us; speedup vs baseline: 1.7502x; 1.7502x over previous
//
#include <hip/hip_runtime.h>
#include <hip/hip_bf16.h>

#define N_NODES 25000
#define N_EDGES 100000
#define E_PAD   100032   // 1563 * 64
#define NSCB    98       // ceil(N_NODES/256) scan blocks
#define NHB     391      // ceil(N_EDGES/256) histogram blocks

typedef __attribute__((ext_vector_type(8))) short bf16x8;
typedef __attribute__((ext_vector_type(4))) float f32x4;

__device__ __forceinline__ unsigned short f2bf(float v) {
  __hip_bfloat16 hb = __float2bfloat16(v);
  return *reinterpret_cast<unsigned short*>(&hb);
}
__device__ __forceinline__ float bf2f(unsigned short u) {
  return __uint_as_float(((unsigned)u) << 16);
}

// Fused prep: blocks [0,128): W2 -> bf16 packed B-fragments (coalesced
// (i,w,s,lane) order). Blocks [128, 128+6250): node prep out/xb/ab1/ab2.
// Blocks [6378, 6378+391): deg histogram from dst (deg zeroed by memset).
__global__ __launch_bounds__(256) void k_pre(const float* __restrict__ x,
    const float* __restrict__ root, const float* __restrict__ b2,
    const float* __restrict__ att, const float* __restrict__ bias,
    const float* __restrict__ W2, const int* __restrict__ ei,
    unsigned char* __restrict__ w2pk,
    float* __restrict__ out, float* __restrict__ xb,
    float* __restrict__ ab1, float* __restrict__ ab2,
    unsigned* __restrict__ deg) {
  __shared__ float lxb[4][64];
  int b = blockIdx.x;
  if (b < 128) {
    int g = b * 256 + threadIdx.x;                 // 32768 threads
    int lane = g & 63, s = (g >> 6) & 3, w = (g >> 8) & 3, i = g >> 10;
    int col = i * 64 + w * 16 + (lane & 15);
    int k0 = s * 32 + (lane >> 4) * 8;
    bf16x8 v;
    #pragma unroll
    for (int j = 0; j < 8; ++j)
      v[j] = (short)f2bf(W2[(size_t)(k0 + j) * 2048 + col]);
    *(bf16x8*)(w2pk + (size_t)g * 16) = v;         // linear: coalesced store
    return;
  }
  if (b >= 128 + 6250) {
    int e = (b - 128 - 6250) * 256 + threadIdx.x;
    if (e < N_EDGES) atomicAdd(deg + ei[N_EDGES + e], 1u);
    return;
  }
  int g = (b - 128) * 256 + threadIdx.x;           // N*64 exact
  int n = g >> 6, o = g & 63;
  const float* xr = x + (size_t)n * 32;
  float ra = bias[o], xa = 0.f;
  #pragma unroll
  for (int i = 0; i < 32; ++i) {
    float xv = xr[i];
    ra += xv * root[i * 64 + o];
    xa += xv * b2[i * 64 + o];
  }
  out[g] = ra;
  xb[g] = xa;
  int ln = threadIdx.x >> 6;
  lxb[ln][o] = xa;
  __syncthreads();
  if (o < 8) {
    int hd = o;
    float s1 = 0.f, s2 = 0.f;
    #pragma unroll
    for (int c = 0; c < 8; ++c) {
      float v = lxb[ln][hd * 8 + c];
      s1 += v * att[hd * 16 + c];
      s2 += v * att[hd * 16 + 8 + c];
    }
    size_t idx = (size_t)n * 8 + hd;
    ab1[idx] = s1; ab2[idx] = s2;
  }
}

// R22/R24 k_main verbatim (measured best: ~87 us, reproduced twice).
// Pair-amortized A-reads, coalesced B-loads from L2-resident packed W2,
// MFMA inline-h prologue, no barriers in the K-loop, no epilogue atomics.
// waves_per_eu(2) is the measured optimum: (2,5) equal, (4) squeezes VGPR
// to 64 and remat-explodes FETCH (R25), quad-amortize/pins/packing all lose.
__global__ __launch_bounds__(256)
__attribute__((amdgpu_waves_per_eu(2)))
void k_main(
    const float* __restrict__ x, const int* __restrict__ ei,
    const float* __restrict__ ef, const float* __restrict__ W1,
    const float* __restrict__ b1,
    const float* __restrict__ att, const float* __restrict__ ab1,
    const float* __restrict__ ab2,
    const unsigned char* __restrict__ w2pk,
    unsigned short* __restrict__ xj_out, float* __restrict__ alpha_out) {
  __shared__ unsigned char lds_h[16384];   // 16 frags x 64 lanes x 16B, linear
  __shared__ float lds_xs[32 * 64];        // [ch][edge] x[src] transposed, f32
  __shared__ float lds_xd[32 * 64];        // [ch][edge] x[dst] transposed, f32
  const int tid = threadIdx.x;
  const int lane = tid & 63;
  const int w = tid >> 6;                  // wave id: owns output cols w*16..+15
  const int e0 = blockIdx.x * 64;
  const int* srcp = ei;
  const int* dstp = ei + N_EDGES;

  // ---- inline h via MFMA (R13 verbatim, proven) ----
  {
    const int l15 = lane & 15;
    const int k0 = (lane >> 4) * 8;
    bf16x8 ha[4], hb[2];
    #pragma unroll
    for (int mt = 0; mt < 4; ++mt) {
      int e = e0 + mt * 16 + l15;
      if (e >= N_EDGES) e = N_EDGES - 1;   // clamped rows masked later
      bf16x8 v;
      if (k0 < 16) {
        const float* ap = ef + (size_t)e * 16 + k0;
        f32x4 a0 = *(const f32x4*)(ap);
        f32x4 a1 = *(const f32x4*)(ap + 4);
        #pragma unroll
        for (int t = 0; t < 4; ++t) {
          v[t]     = (short)f2bf(a0[t]);
          v[t + 4] = (short)f2bf(a1[t]);
        }
      } else {
        #pragma unroll
        for (int t = 0; t < 8; ++t) v[t] = 0;
      }
      ha[mt] = v;
    }
    #pragma unroll
    for (int nt = 0; nt < 2; ++nt) {
      int col = w * 32 + nt * 16 + l15;
      bf16x8 v;
      if (k0 < 16) {
        #pragma unroll
        for (int j = 0; j < 8; ++j)
          v[j] = (short)f2bf(W1[(k0 + j) * 128 + col]);
      } else {
        #pragma unroll
        for (int j = 0; j < 8; ++j) v[j] = 0;
      }
      hb[nt] = v;
    }
    const int lpb = (lane >> 4) * 4;               // output row base within 16
    const int byt = (lane & 7) * 2;                // byte within 16B frag slot
    #pragma unroll
    for (int nt = 0; nt < 2; ++nt) {
      float bv = b1[w * 32 + nt * 16 + l15];
      const int hi = (nt * 2 + (l15 >> 3)) << 4;   // reader-lane hi nibble
      #pragma unroll
      for (int mt = 0; mt < 4; ++mt) {
        f32x4 acc = {bv, bv, bv, bv};
        acc = __builtin_amdgcn_mfma_f32_16x16x32_bf16(ha[mt], hb[nt], acc, 0, 0, 0);
        unsigned base = (unsigned)(mt * 4 + w) * 1024u + (unsigned)hi * 16u + (unsigned)byt;
        #pragma unroll
        for (int r = 0; r < 4; ++r) {
          float hv = acc[r] > 0.f ? acc[r] : 0.f;
          *(unsigned short*)(lds_h + base + (lpb + r) * 16) = f2bf(hv);
        }
      }
    }
  }

  // ---- gather x rows for src/dst (transposed into LDS, f32) ----
  {
    int m = tid & 63;
    int half = (tid >> 6) & 1;
    int which = tid >> 7;
    int eIdx = e0 + m; if (eIdx >= N_EDGES) eIdx = N_EDGES - 1;
    int node = which ? dstp[eIdx] : srcp[eIdx];
    const f32x4* xr = (const f32x4*)(x + (size_t)node * 32 + half * 16);
    float* lx = which ? lds_xd : lds_xs;
    #pragma unroll
    for (int q = 0; q < 4; ++q) {
      f32x4 vv = xr[q];
      int i0 = half * 16 + q * 4;
      #pragma unroll
      for (int j = 0; j < 4; ++j) lx[(i0 + j) * 64 + m] = vv[j];
    }
  }
  __syncthreads();

  // ---- K-loop: pair-amortized, coalesced B-loads ----
  const unsigned char* bgp = w2pk + (size_t)w * 4096 + (size_t)lane * 16;
  f32x4 xj_acc[4] = {};
  f32x4 xi_acc[4] = {};
  const int rg4 = ((lane >> 4) & 3) * 4;
  const int lb16 = lane * 16;

  #pragma unroll 1
  for (int p = 0; p < 16; ++p) {
    const int i = 2 * p;
    bf16x8 bA[4], bB[4];
    #pragma unroll
    for (int s = 0; s < 4; ++s) {
      bA[s] = *(const bf16x8*)(bgp + (size_t)i * 16384 + s * 1024);
      bB[s] = *(const bf16x8*)(bgp + (size_t)(i + 1) * 16384 + s * 1024);
    }
    #pragma unroll
    for (int mt = 0; mt < 4; ++mt) {
      f32x4 gA = {0.f, 0.f, 0.f, 0.f};
      f32x4 gB = {0.f, 0.f, 0.f, 0.f};
      #pragma unroll
      for (int s = 0; s < 4; ++s) {
        bf16x8 a = *(const bf16x8*)(lds_h + (mt * 4 + s) * 1024 + lb16);
        gA = __builtin_amdgcn_mfma_f32_16x16x32_bf16(a, bA[s], gA, 0, 0, 0);
        gB = __builtin_amdgcn_mfma_f32_16x16x32_bf16(a, bB[s], gB, 0, 0, 0);
      }
      f32x4 xsv0 = *(const f32x4*)(lds_xs + i * 64 + mt * 16 + rg4);
      f32x4 xdv0 = *(const f32x4*)(lds_xd + i * 64 + mt * 16 + rg4);
      f32x4 xsv1 = *(const f32x4*)(lds_xs + (i + 1) * 64 + mt * 16 + rg4);
      f32x4 xdv1 = *(const f32x4*)(lds_xd + (i + 1) * 64 + mt * 16 + rg4);
      #pragma unroll
      for (int r = 0; r < 4; ++r) {
        xj_acc[mt][r] += xsv0[r] * gA[r] + xsv1[r] * gB[r];
        xi_acc[mt][r] += xdv0[r] * gA[r] + xdv1[r] * gB[r];
      }
    }
  }

  // ---- epilogue: xj bf16 store + logits ----
  const int h2 = (lane >> 3) & 1;
  const int cc = lane & 7;
  const int head = 2 * w + h2;
  const float a1v = att[head * 16 + cc];
  const float a2v = att[head * 16 + 8 + cc];
  #pragma unroll
  for (int mt = 0; mt < 4; ++mt) {
    #pragma unroll
    for (int r = 0; r < 4; ++r) {
      int row = mt * 16 + rg4 + r;
      int eIdx = e0 + row;
      xj_out[(size_t)eIdx * 64 + w * 16 + (lane & 15)] = f2bf(xj_acc[mt][r]);
      float v = xi_acc[mt][r] * a1v + xj_acc[mt][r] * a2v;
      v += __shfl_xor(v, 1);
      v += __shfl_xor(v, 2);
      v += __shfl_xor(v, 4);
      if (cc == 0 && eIdx < N_EDGES) {
        int d = dstp[eIdx];
        float lg = v + ab1[(size_t)d * 8 + head] + ab2[(size_t)srcp[eIdx] * 8 + head];
        lg = lg > 0.f ? lg : 0.2f * lg;
        alpha_out[(size_t)eIdx * 8 + head] = lg;
      }
    }
  }
}

// Block-local exclusive scan of deg + one atomicAdd(gbase) per block for the
// absolute segment base (arrival order; contiguity is all that matters).
__global__ __launch_bounds__(256) void k_scan(const unsigned* __restrict__ deg,
    unsigned* __restrict__ off, unsigned* __restrict__ gbase) {
  __shared__ unsigned sd[256];
  __shared__ unsigned blockbase;
  int tid = threadIdx.x;
  int n = blockIdx.x * 256 + tid;
  unsigned v = (n < N_NODES) ? deg[n] : 0u;
  sd[tid] = v;
  __syncthreads();
  #pragma unroll
  for (int ofs = 1; ofs < 256; ofs <<= 1) {
    unsigned t = (tid >= ofs) ? sd[tid - ofs] : 0u;
    __syncthreads();
    sd[tid] += t;
    __syncthreads();
  }
  if (tid == 255) blockbase = atomicAdd(gbase, sd[255]);
  __syncthreads();
  if (n < N_NODES) off[n] = blockbase + sd[tid] - v;   // absolute segment start
}

// Fill CSR edge lists: pos = off[d]++ (off[n] ends at segment end; k_agg
// recovers base = off[n] - deg[n]).
__global__ __launch_bounds__(256) void k_fill(const int* __restrict__ ei,
    unsigned* __restrict__ off, unsigned* __restrict__ elist) {
  int e = blockIdx.x * 256 + threadIdx.x;
  if (e >= N_EDGES) return;
  int d = ei[N_EDGES + e];
  unsigned pos = atomicAdd(off + d, 1u);
  elist[pos] = (unsigned)e;
}

// Gather-aggregate: per (node, o): softmax over incoming edges (2 uniform
// loops, wave = exactly one node), + deg*bias, + ELU. No atomics.
__global__ __launch_bounds__(256) void k_agg(const unsigned* __restrict__ off,
    const unsigned* __restrict__ deg,
    const unsigned* __restrict__ elist, const float* __restrict__ alpha,
    const unsigned short* __restrict__ xj, const float* __restrict__ bias,
    float* __restrict__ out) {
  int g = blockIdx.x * 256 + threadIdx.x;          // N*64 exact
  int n = g >> 6, o = g & 63, hd = o >> 3;
  unsigned dg = deg[n];
  unsigned base = off[n] - dg;                     // off ended at segment end
  float m = -1e30f;
  for (unsigned j = 0; j < dg; ++j) {
    unsigned e = elist[base + j];
    m = fmaxf(m, alpha[(size_t)e * 8 + hd]);
  }
  float s = 0.f, acc = 0.f;
  for (unsigned j = 0; j < dg; ++j) {
    unsigned e = elist[base + j];
    float p = expf(alpha[(size_t)e * 8 + hd] - m);
    s += p;
    acc += p * bf2f(xj[(size_t)e * 64 + o]);
  }
  float val = out[g] + acc / (s + 1e-16f) + (float)dg * bias[o];
  out[g] = val > 0.f ? val : expm1f(val);
}

extern "C" void kernel_launch(void* const* d_in, const int* in_sizes, int n_in,
                              void* d_out, int out_size, void* d_ws, size_t ws_size,
                              hipStream_t stream) {
  const float* x    = (const float*)d_in[0];
  const int*   eidx = (const int*)d_in[1];
  const float* ef   = (const float*)d_in[2];
  const float* W1   = (const float*)d_in[3];
  const float* b1   = (const float*)d_in[4];
  const float* W2   = (const float*)d_in[5];
  const float* b2   = (const float*)d_in[6];
  const float* att  = (const float*)d_in[7];
  const float* bias = (const float*)d_in[8];
  const float* root = (const float*)d_in[9];
  float* out = (float*)d_out;
  char* ws = (char*)d_ws;

  // workspace layout (256B aligned), total ~25.2 MB
  unsigned char* w2pk = (unsigned char*)(ws + 0);           // 512 KB packed B-frags
  float* xb    = (float*)(ws + 524288);                     // N*64 f32
  float* ab1   = (float*)(ws + 6924288);                    // N*8 f32
  float* ab2   = (float*)(ws + 7724288);                    // N*8 f32
  unsigned short* xj_ws = (unsigned short*)(ws + 8524288);  // E_PAD*64 bf16
  float* al_ws = (float*)(ws + 21328384);                   // E_PAD*8 f32
  unsigned* deg   = (unsigned*)(ws + 24529408);             // N u32 (pad 100352)
  unsigned* gbase = (unsigned*)(ws + 24629760);             // 1 u32 (pad 256)
  unsigned* off   = (unsigned*)(ws + 24630016);             // N u32 (pad 100352)
  unsigned* elist = (unsigned*)(ws + 24730368);             // E u32

  hipMemsetAsync(deg, 0, 100352 + 256, stream);             // deg + gbase
  k_pre  <<<128 + 6250 + NHB, 256, 0, stream>>>(x, root, b2, att, bias,
                                                W2, eidx, w2pk, out, xb, ab1, ab2, deg);
  k_main <<<E_PAD / 64, 256, 0, stream>>>(x, eidx, ef, W1, b1, att, ab1, ab2,
                                          w2pk, xj_ws, al_ws);
  k_scan <<<NSCB, 256, 0, stream>>>(deg, off, gbase);
  k_fill <<<NHB, 256, 0, stream>>>(eidx, off, elist);
  k_agg  <<<N_NODES * 64 / 256, 256, 0, stream>>>(off, deg, elist, al_ws,
                                                  xj_ws, bias, out);
}